// Round 6
// baseline (32.907 us; speedup 1.0000x reference)
//
#include <hip/hip_runtime.h>

constexpr int N_SAMP = 2048;
constexpr int T_DIM  = 256;
constexpr int D_DIM  = 64;
constexpr int NBINS  = 64;

typedef float  f4  __attribute__((ext_vector_type(4)));   // native vector: ok for nontemporal builtins

// One block per t (grid = 256 = #CUs), 1024 threads.
// Phase 1: LDS integer histogram for all 64 d at this t (deterministic).
// Phase 2: partial loss vs densities (dens prefetched at kernel entry so the
//          4 MB dens stream hides under phase 1), one float4/uint4 per thread.
// x is streamed with nontemporal loads (read-once, no reuse) and unroll 8
// for deep MLP.
__global__ __launch_bounds__(1024) void histo_loss_kernel(
    const float* __restrict__ x,      // [N, T, D]
    const float* __restrict__ dens,   // [T, D, NBINS]
    const float* __restrict__ bmin,   // [T, D]
    const float* __restrict__ bmax,   // [T, D]
    float* __restrict__ partial)      // [T]  (d_ws)
{
    __shared__ alignas(16) unsigned int hist[D_DIM * NBINS];   // 16 KB
    const int t   = blockIdx.x;
    const int tid = threadIdx.x;

    // ---- issue independent prefetches FIRST (no deps on LDS or hist) ----
    const f4 dv = __builtin_nontemporal_load(
        reinterpret_cast<const f4*>(dens + (size_t)t * (D_DIM * NBINS)) + tid);

    const int c  = tid & 15;   // which float4 within the 64-float row
    const int r  = tid >> 4;   // row offset within a 64-row chunk
    const int d0 = c * 4;
    const f4 a4 = *reinterpret_cast<const f4*>(bmin + t * D_DIM + d0);
    const f4 b4 = *reinterpret_cast<const f4*>(bmax + t * D_DIM + d0);

    // ---- zero LDS histogram ----
    for (int i = tid; i < D_DIM * NBINS; i += 1024) hist[i] = 0u;

    const float a[4]  = {a4.x, a4.y, a4.z, a4.w};
    const float bb[4] = {b4.x, b4.y, b4.z, b4.w};
    float s[4];
#pragma unroll
    for (int j = 0; j < 4; ++j) s[j] = (float)NBINS / (bb[j] - a[j]);
    __syncthreads();

    const f4* __restrict__ x4 = reinterpret_cast<const f4*>(x);
    const size_t row4 = (size_t)(T_DIM * D_DIM / 4);     // 4096 float4 per n
    const size_t base = (size_t)r * row4 + (size_t)t * (D_DIM / 4) + (size_t)c;

#pragma unroll 8
    for (int it = 0; it < N_SAMP / 64; ++it) {
        f4 v4 = __builtin_nontemporal_load(x4 + base + (size_t)it * 64 * row4);
        float v[4] = {v4.x, v4.y, v4.z, v4.w};
#pragma unroll
        for (int j = 0; j < 4; ++j) {
            float vv = v[j];
            if (vv >= a[j] && vv <= bb[j]) {
                // in-range => (vv-a[j]) >= 0, so int truncation == floor
                int idx = (int)((vv - a[j]) * s[j]);
                idx = idx > NBINS - 1 ? NBINS - 1 : idx;
                atomicAdd(&hist[(d0 + j) * NBINS + idx], 1u);
            }
        }
    }
    __syncthreads();

    // ---- Phase 2: partial loss (dens already in registers) ----
    const float invN = 1.0f / (float)N_SAMP;
    uint4 hv = *reinterpret_cast<const uint4*>(hist + tid * 4);
    float sum = fabsf((float)hv.x * invN - dv.x)
              + fabsf((float)hv.y * invN - dv.y)
              + fabsf((float)hv.z * invN - dv.z)
              + fabsf((float)hv.w * invN - dv.w);
#pragma unroll
    for (int off = 32; off > 0; off >>= 1) sum += __shfl_down(sum, off, 64);

    __shared__ float wpart[16];
    if ((tid & 63) == 0) wpart[tid >> 6] = sum;
    __syncthreads();
    if (tid < 16) {
        float v = wpart[tid];
#pragma unroll
        for (int off = 8; off > 0; off >>= 1) v += __shfl_down(v, off, 16);
        if (tid == 0) partial[t] = v;
    }
}

// One wave. Lane i reads partial[4i..4i+3]; shuffle tree; lane 0 writes out.
__global__ __launch_bounds__(64) void histo_final_reduce(
    const float* __restrict__ partial, float* __restrict__ out)
{
    const int lane = threadIdx.x;
    f4 p = reinterpret_cast<const f4*>(partial)[lane];
    float v = (p.x + p.y) + (p.z + p.w);
#pragma unroll
    for (int off = 32; off > 0; off >>= 1) v += __shfl_down(v, off, 64);
    if (lane == 0)
        out[0] = v * (1.0f / (float)(T_DIM * D_DIM * NBINS));
}

extern "C" void kernel_launch(void* const* d_in, const int* in_sizes, int n_in,
                              void* d_out, int out_size, void* d_ws, size_t ws_size,
                              hipStream_t stream)
{
    const float* x    = (const float*)d_in[0];   // x_fake  [N,T,D]
    const float* dens = (const float*)d_in[1];   // densities [T,D,NBINS]
    const float* bmin = (const float*)d_in[2];   // [T,D]
    const float* bmax = (const float*)d_in[3];   // [T,D]
    float* out     = (float*)d_out;
    float* partial = (float*)d_ws;               // 256 floats

    histo_loss_kernel<<<T_DIM, 1024, 0, stream>>>(x, dens, bmin, bmax, partial);
    histo_final_reduce<<<1, 64, 0, stream>>>(partial, out);
}

// Round 7
// 26.859 us; speedup vs baseline: 1.2252x; 1.2252x over previous
//
#include <hip/hip_runtime.h>

constexpr int N_SAMP = 2048;
constexpr int T_DIM  = 256;
constexpr int D_DIM  = 64;
constexpr int NBINS  = 64;
constexpr int DH     = 32;            // d-columns per block (D split in halves)
constexpr int NBLK   = T_DIM * 2;     // 512 blocks = 2 per CU

// One block per (t, D-half). 512 threads, 8 KB LDS histogram.
// Histogram + loss are decomposable over d, so no cross-block merge needed.
// 2 independent blocks/CU -> barrier/epilogue tails overlap across blocks.
__global__ __launch_bounds__(512) void histo_loss_kernel(
    const float* __restrict__ x,      // [N, T, D]
    const float* __restrict__ dens,   // [T, D, NBINS]
    const float* __restrict__ bmin,   // [T, D]
    const float* __restrict__ bmax,   // [T, D]
    float* __restrict__ partial)      // [NBLK]  (d_ws)
{
    __shared__ alignas(16) unsigned int hist[DH * NBINS];   // 8 KB
    const int b   = blockIdx.x;
    const int t   = b >> 1;
    const int dh  = b & 1;            // which D-half
    const int tid = threadIdx.x;

    // ---- independent prefetch of this block's dens slice (2048 floats) ----
    const float4 dv = *(reinterpret_cast<const float4*>(
        dens + (size_t)t * (D_DIM * NBINS) + dh * (DH * NBINS)) + tid);

    const int c  = tid & 7;           // which float4 within the 32-float half-row
    const int r  = tid >> 3;          // row offset within a 64-row chunk
    const int d0 = dh * DH + c * 4;   // global d of this thread's quad

    const float4 a4 = *reinterpret_cast<const float4*>(bmin + t * D_DIM + d0);
    const float4 b4 = *reinterpret_cast<const float4*>(bmax + t * D_DIM + d0);

    // ---- zero LDS histogram ----
    for (int i = tid; i < DH * NBINS; i += 512) hist[i] = 0u;

    const float a[4]  = {a4.x, a4.y, a4.z, a4.w};
    const float bb[4] = {b4.x, b4.y, b4.z, b4.w};
    float s[4];
#pragma unroll
    for (int j = 0; j < 4; ++j) s[j] = (float)NBINS / (bb[j] - a[j]);
    __syncthreads();

    const float4* __restrict__ x4 = reinterpret_cast<const float4*>(x);
    const size_t row4 = (size_t)(T_DIM * D_DIM / 4);   // 4096 float4 per n
    const size_t base = (size_t)r * row4
                      + (size_t)t * (D_DIM / 4) + (size_t)dh * (DH / 4)
                      + (size_t)c;
    const int dloc = c * 4;           // local d within this half

#pragma unroll 4
    for (int it = 0; it < N_SAMP / 64; ++it) {
        float4 v4 = x4[base + (size_t)it * 64 * row4];
        float v[4] = {v4.x, v4.y, v4.z, v4.w};
#pragma unroll
        for (int j = 0; j < 4; ++j) {
            float vv = v[j];
            if (vv >= a[j] && vv <= bb[j]) {
                // in-range => (vv-a[j]) >= 0, so int truncation == floor
                int idx = (int)((vv - a[j]) * s[j]);
                idx = idx > NBINS - 1 ? NBINS - 1 : idx;
                atomicAdd(&hist[(dloc + j) * NBINS + idx], 1u);
            }
        }
    }
    __syncthreads();

    // ---- Phase 2: partial loss over this block's 2048 bins ----
    const float invN = 1.0f / (float)N_SAMP;
    uint4 hv = *reinterpret_cast<const uint4*>(hist + tid * 4);
    float sum = fabsf((float)hv.x * invN - dv.x)
              + fabsf((float)hv.y * invN - dv.y)
              + fabsf((float)hv.z * invN - dv.z)
              + fabsf((float)hv.w * invN - dv.w);
#pragma unroll
    for (int off = 32; off > 0; off >>= 1) sum += __shfl_down(sum, off, 64);

    __shared__ float wpart[8];
    if ((tid & 63) == 0) wpart[tid >> 6] = sum;
    __syncthreads();
    if (tid < 8) {
        float v = wpart[tid];
#pragma unroll
        for (int off = 4; off > 0; off >>= 1) v += __shfl_down(v, off, 8);
        if (tid == 0) partial[b] = v;
    }
}

// One wave. Lane i reads partial[8i..8i+7]; shuffle tree; lane 0 writes out.
__global__ __launch_bounds__(64) void histo_final_reduce(
    const float* __restrict__ partial, float* __restrict__ out)
{
    const int lane = threadIdx.x;
    const float4* p4 = reinterpret_cast<const float4*>(partial);
    float4 p = p4[lane * 2];
    float4 q = p4[lane * 2 + 1];
    float v = ((p.x + p.y) + (p.z + p.w)) + ((q.x + q.y) + (q.z + q.w));
#pragma unroll
    for (int off = 32; off > 0; off >>= 1) v += __shfl_down(v, off, 64);
    if (lane == 0)
        out[0] = v * (1.0f / (float)(T_DIM * D_DIM * NBINS));
}

extern "C" void kernel_launch(void* const* d_in, const int* in_sizes, int n_in,
                              void* d_out, int out_size, void* d_ws, size_t ws_size,
                              hipStream_t stream)
{
    const float* x    = (const float*)d_in[0];   // x_fake  [N,T,D]
    const float* dens = (const float*)d_in[1];   // densities [T,D,NBINS]
    const float* bmin = (const float*)d_in[2];   // [T,D]
    const float* bmax = (const float*)d_in[3];   // [T,D]
    float* out     = (float*)d_out;
    float* partial = (float*)d_ws;               // 512 floats

    histo_loss_kernel<<<NBLK, 512, 0, stream>>>(x, dens, bmin, bmax, partial);
    histo_final_reduce<<<1, 64, 0, stream>>>(partial, out);
}